// Round 9
// baseline (479.958 us; speedup 1.0000x reference)
//
#include <hip/hip_runtime.h>
#include <cstdint>

// Problem constants
#define Bn   32
#define Cn   256
#define Hn   56
#define Wn   56
#define HWn  (Hn*Wn)           // 3136
#define NPIX (Bn*HWn)          // 100352
#define WELEMS (Cn*Cn*9)       // 589824
#define EPSv 1e-5f

// padded channels-last activation plane: [b][58 rows][58 cols][256 ci] i8
// per-pixel 256B block stored XOR-swizzled: 16B slot s lives at s ^ (padded_col & 15)
#define PR   58
#define PPLANE (PR*PR)         // 3364

// ws layout (floats for wsf): [8..43] = 36 per-block |w| partials (plain
// stores, no init needed); [64..319] = F_SUM; [320..575] = F_SQ (zeroed by
// pack_all blocks 0/1, which complete before conv via stream ordering).
#define F_WPART 8
#define F_SUM   64
#define F_SQ    320
#define WPK_OFF  4096                     // i8 wpk[kc=36][co=256][64]  (A repack)
#define WPK_BYTES WELEMS                  // 589824
#define ACT_OFF  (WPK_OFF + WPK_BYTES)    // 593920 (16B aligned)
#define ACT_BYTES (Bn*PPLANE*Cn)          // 27553792

typedef int v4i __attribute__((ext_vector_type(4)));

#define GLOBAL_AS __attribute__((address_space(1)))
#define LDS_AS    __attribute__((address_space(3)))

// ---------------------------------------------------------------------------
// Fused packing kernel (unchanged — verified rounds 3-8).
__global__ void pack_all(const float* __restrict__ x,
                         const float* __restrict__ w,
                         float* __restrict__ wsf,
                         uint8_t* __restrict__ wpk,
                         uint8_t* __restrict__ act) {
    if (blockIdx.x < 392) {
        // --- BN-stats zero-init (replaces the memset dispatch) ---
        if (blockIdx.x < 2)
            wsf[F_SUM + blockIdx.x * 256 + threadIdx.x] = 0.0f;

        int v = blockIdx.x * 256 + threadIdx.x;   // 0..100351
        // --- halo zeroing: 32 batches * 228 border pixels = 7296 ---
        if (v < 7296) {
            int b = v / 228;
            int r = v - b * 228;
            int y, xx;
            if (r < 58)       { y = 0;  xx = r; }
            else if (r < 116) { y = 57; xx = r - 58; }
            else { int r2 = r - 116; y = 1 + (r2 >> 1); xx = (r2 & 1) * 57; }
            uint4* d = (uint4*)(act + ((size_t)(b * PR + y) * PR + xx) * 256);
            uint4 z = make_uint4(0, 0, 0, 0);
            #pragma unroll
            for (int i = 0; i < 16; i++) d[i] = z;
        }
        // --- interior pack with per-pixel XOR swizzle ---
        int b = v / HWn;
        int p = v - b * HWn;
        int y = p / Wn;
        int xx = p - y * Wn;
        const float* xp = x + (size_t)b * Cn * HWn + p;
        int key = (xx + 1) & 15;
        uint32_t* dst = (uint32_t*)(act + ((size_t)(b * PR + (y + 1)) * PR + (xx + 1)) * 256);
        #pragma unroll
        for (int slot = 0; slot < 16; slot++) {
            uint32_t rr[4];
            #pragma unroll
            for (int cw = 0; cw < 4; cw++) {
                uint32_t r = 0;
                #pragma unroll
                for (int j = 0; j < 4; j++) {
                    uint32_t sgn = __float_as_uint(xp[(size_t)(slot * 16 + cw * 4 + j) * HWn]) >> 31;
                    r |= (sgn ? 0xFFu : 0x01u) << (j * 8);
                }
                rr[cw] = r;
            }
            *(uint4*)(dst + (size_t)((slot ^ key) * 4)) = make_uint4(rr[0], rr[1], rr[2], rr[3]);
        }
    } else {
        int u = (blockIdx.x - 392) * 256 + threadIdx.x;   // 36*256 = 9216
        int co = u / 36;
        int kc = u - co * 36;
        int t  = kc >> 2;          // tap
        int s  = kc & 3;           // 64-ci chunk
        const float* wp = w + (size_t)co * 2304 + t;      // OIHW
        uint32_t* dst = (uint32_t*)(wpk + ((size_t)kc * 256 + co) * 64);
        float sabs = 0.0f;
        #pragma unroll
        for (int cw = 0; cw < 16; cw++) {
            uint32_t r = 0;
            #pragma unroll
            for (int j = 0; j < 4; j++) {
                int ci = s * 64 + cw * 4 + j;
                float wv = wp[(size_t)ci * 9];
                sabs += fminf(fabsf(wv), 1.0f);
                r |= ((__float_as_uint(wv) >> 31) ? 0xFFu : 0x01u) << (j * 8);
            }
            dst[cw] = r;
        }
        #pragma unroll
        for (int off = 32; off; off >>= 1) sabs += __shfl_down(sabs, off);
        __shared__ float sh[4];
        if ((threadIdx.x & 63) == 0) sh[threadIdx.x >> 6] = sabs;
        __syncthreads();
        if (threadIdx.x == 0)   // plain store: no atomic, no init required
            wsf[F_WPART + (blockIdx.x - 392)] = sh[0] + sh[1] + sh[2] + sh[3];
    }
}

// ---------------------------------------------------------------------------
// Per-wave conv body, templated on N-fragment count (4 or 3) so every index
// is compile-time (rule: runtime-indexed reg arrays spill to scratch).
// K-loop = round-4/8 structure: runtime t-loop, 4 unrolled chunk-steps,
// distance-1 A prefetch (4-wave-/SIMD TLP now hides the latency), single bf.
template<int NF>
__device__ __forceinline__ void conv_body(
    const uint8_t* lds, const uint8_t* abase,
    const float* __restrict__ x, float* __restrict__ wsf,
    float* __restrict__ out, float mv,
    int f0, int l15, int l4, int co_w, int pbase) {

    // Tap-walking state for t=0 (dh=-1, dw=-1): window corner, local coords.
    int pixb[NF], key[NF];
    #pragma unroll
    for (int ni = 0; ni < NF; ni++) {
        int n  = (f0 + ni) * 16 + l15;
        int r_ = n / 56;
        int c_ = n - r_ * 56;
        pixb[ni] = (r_ * 58 + c_) * 256;
        key[ni]  = c_ & 15;
    }

    // A prologue: kc = 0.
    v4i af[4];
    #pragma unroll
    for (int mi = 0; mi < 4; mi++)
        af[mi] = *(const v4i*)(abase + mi * 1024);

    v4i acc[4][NF] = {};

#define STEP(S)                                                                \
    {                                                                          \
        v4i bf[NF];                                                            \
        _Pragma("unroll")                                                      \
        for (int ni = 0; ni < NF; ni++)                                        \
            bf[ni] = *(const v4i*)(lds + pixb[ni] +                            \
                                   ((((S) * 4 + l4) ^ key[ni]) << 4));         \
        _Pragma("unroll")                                                      \
        for (int ni = 0; ni < NF; ni++) {                                      \
            _Pragma("unroll")                                                  \
            for (int mi = 0; mi < 4; mi++)                                     \
                acc[mi][ni] = __builtin_amdgcn_mfma_i32_16x16x64_i8(           \
                    af[mi], bf[ni], acc[mi][ni], 0, 0, 0);                     \
        }                                                                      \
        {                                                                      \
            int kcn = t4 + (S) + 1;                                            \
            kcn = kcn > 35 ? 35 : kcn;   /* tail: redundant reload, unused */  \
            const uint8_t* ap = abase + (size_t)kcn * 16384;                   \
            _Pragma("unroll")                                                  \
            for (int mi = 0; mi < 4; mi++)                                     \
                af[mi] = *(const v4i*)(ap + mi * 1024);                        \
        }                                                                      \
    }

    #pragma unroll 1
    for (int t = 0; t < 9; t++) {
        const int t4 = t * 4;
        STEP(0)
        STEP(1)
        STEP(2)
        STEP(3)
        // Tap-walk t -> t+1: dw cycles -1,0,1 (ddw=+1, dtoff=+256), wrapping
        // at t=2,5 (ddw=-2, dtoff=(58-2)*256); t=8 is the end (no-op).
        const int wrap  = (t == 2 || t == 5);
        const int dtoff = (t == 8) ? 0 : (wrap ? 56 * 256 : 256);
        const int ddw   = (t == 8) ? 0 : (wrap ? -2 : 1);
        #pragma unroll
        for (int ni = 0; ni < NF; ni++) {
            pixb[ni] += dtoff;
            key[ni]   = (key[ni] + ddw) & 15;
        }
    }
#undef STEP

    // Epilogue: scale + shortcut + store + per-channel partial stats.
    float ssum[4][4] = {}, ssq[4][4] = {};
    #pragma unroll
    for (int mi = 0; mi < 4; mi++) {
        #pragma unroll
        for (int ni = 0; ni < NF; ni++) {
            v4i a = acc[mi][ni];
            #pragma unroll
            for (int q = 0; q < 4; q++) {
                int co = co_w + mi * 16 + l4 * 4 + q;
                size_t idx = (size_t)pbase + (size_t)co * HWn + ((f0 + ni) * 16 + l15);
                float val = fmaf(mv, (float)a[q], x[idx]);
                out[idx] = val;
                ssum[mi][q] += val;
                ssq[mi][q]  += val * val;
            }
        }
    }
    // Reduce across the 16 lanes (l15) sharing each channel, then atomics.
    #pragma unroll
    for (int mi = 0; mi < 4; mi++) {
        #pragma unroll
        for (int q = 0; q < 4; q++) {
            float s = ssum[mi][q], sq = ssq[mi][q];
            #pragma unroll
            for (int off = 1; off < 16; off <<= 1) {
                s  += __shfl_xor(s, off);
                sq += __shfl_xor(sq, off);
            }
            if (l15 == 0) {
                int co = co_w + mi * 16 + l4 * 4 + q;
                atomicAdd(&wsf[F_SUM + co], s);
                atomicAdd(&wsf[F_SQ  + co], sq);
            }
        }
    }
}

// ---------------------------------------------------------------------------
// Binary conv as implicit GEMM on the i8 matrix pipe, LDS-staged B.
// Round-9: 8 waves / 512 threads, wave (g,h): co-group g (4 M-frags, keeps
// LDS-reads/MFMA at 0.25) x N-half h (frags 0-3 or 4-6). acc 64/48 regs ->
// total ~116 <= 128 -> __launch_bounds__(512,4): 2 blocks/CU, 4 waves/SIMD
// (vs 2/SIMD for every acc[4][7] variant, rounds 2-8 — occupancy steps are
// 8/4/2 at VGPR 64/128/256, there is no 3-wave level).
__global__ __launch_bounds__(512, 4) void conv_mfma(
    const uint8_t* __restrict__ act, const uint8_t* __restrict__ wpk,
    const float* __restrict__ x, float* __restrict__ wsf,
    float* __restrict__ out) {
    __shared__ uint4 ldsv[3712];              // 59392 B = 58 chunks of 1KB
    uint8_t* lds = (uint8_t*)ldsv;

    const int tid  = threadIdx.x;
    const int lane = tid & 63;
    const int wid  = tid >> 6;                // 0..7
    const int l15  = lane & 15;
    const int l4   = lane >> 4;               // 0..3
    const int g    = wid >> 1;                // co-group 0..3
    const int h    = wid & 1;                 // N-half

    const int bx = blockIdx.x;                // 0..895
    const int b  = bx / 28;
    const int y0 = (bx - b * 28) * 2;         // first output image row

    // Stage padded rows y0..y0+3 via async global->LDS DMA: 58 x 1KB chunks,
    // wave w issues chunks {w, w+8, ...} back-to-back, no waits here.
    {
        const uint8_t* src = act + ((size_t)b * PR + y0) * PR * 256;
        #pragma unroll
        for (int j = 0; j < 8; j++) {
            int c = wid + j * 8;               // wave-uniform
            if (c < 58) {
                __builtin_amdgcn_global_load_lds(
                    (const GLOBAL_AS uint32_t*)(const void*)(src + c * 1024 + lane * 16),
                    (LDS_AS uint32_t*)(void*)(lds + c * 1024),
                    16, 0, 0);
            }
        }
    }

    // mean(|clip(w)|) from the 36 per-block partials (uniform, cheap, L2-hit).
    float wabs = 0.0f;
    #pragma unroll
    for (int j = 0; j < 36; j++) wabs += wsf[F_WPART + j];
    const float mv = wabs * (1.0f / (float)WELEMS);

    const uint8_t* abase = wpk + (g * 64 + l15) * 64 + l4 * 16;
    const int co_w  = g * 64;
    const int pbase = b * (Cn * HWn) + y0 * 56;

    __syncthreads();   // drains vmcnt(0): all LDS-DMA chunks resident

    if (h == 0)
        conv_body<4>(lds, abase, x, wsf, out, mv, 0, l15, l4, co_w, pbase);
    else
        conv_body<3>(lds, abase, x, wsf, out, mv, 4, l15, l4, co_w, pbase);
}

// ---------------------------------------------------------------------------
// BN finalize (per-plane, from fused stats) + normalize + ReLU, in place.
__global__ void epilogue_kernel(float* __restrict__ out,
                                const float* __restrict__ wsf,
                                const float* __restrict__ g,
                                const float* __restrict__ bt) {
    int plane = blockIdx.x;   // b*256 + c
    int c = plane & 255;
    const float n = (float)(Bn * HWn);
    float mean = wsf[F_SUM + c] / n;
    float var  = wsf[F_SQ + c] / n - mean * mean;
    float sc = g[c] * rsqrtf(var + EPSv);
    float sh = bt[c] - mean * sc;
    float4* o4 = (float4*)(out + (size_t)plane * HWn);
    for (int i = threadIdx.x; i < HWn / 4; i += 256) {
        float4 v = o4[i];
        v.x = fmaxf(fmaf(v.x, sc, sh), 0.0f);
        v.y = fmaxf(fmaf(v.y, sc, sh), 0.0f);
        v.z = fmaxf(fmaf(v.z, sc, sh), 0.0f);
        v.w = fmaxf(fmaf(v.w, sc, sh), 0.0f);
        o4[i] = v;
    }
}

// ---------------------------------------------------------------------------
extern "C" void kernel_launch(void* const* d_in, const int* in_sizes, int n_in,
                              void* d_out, int out_size, void* d_ws, size_t ws_size,
                              hipStream_t stream) {
    const float* x     = (const float*)d_in[0];
    const float* w     = (const float*)d_in[1];
    const float* gamma = (const float*)d_in[2];
    const float* beta  = (const float*)d_in[3];
    float* out = (float*)d_out;

    float*   wsf = (float*)d_ws;
    uint8_t* wpk = (uint8_t*)d_ws + WPK_OFF;
    uint8_t* act = (uint8_t*)d_ws + ACT_OFF;

    pack_all<<<dim3(428), dim3(256), 0, stream>>>(x, w, wsf, wpk, act);
    conv_mfma<<<dim3(896), dim3(512), 0, stream>>>(act, wpk, x, wsf, out);
    epilogue_kernel<<<dim3(Bn * Cn), dim3(256), 0, stream>>>(out, wsf, gamma, beta);
}

// Round 10
// 397.083 us; speedup vs baseline: 1.2087x; 1.2087x over previous
//
#include <hip/hip_runtime.h>
#include <cstdint>

// Problem constants
#define Bn   32
#define Cn   256
#define Hn   56
#define Wn   56
#define HWn  (Hn*Wn)           // 3136
#define NPIX (Bn*HWn)          // 100352
#define WELEMS (Cn*Cn*9)       // 589824
#define EPSv 1e-5f

// padded channels-last activation plane: [b][58 rows][58 cols][256 ci] i8
// per-pixel 256B block stored XOR-swizzled: 16B slot s lives at s ^ (padded_col & 15)
#define PR   58
#define PPLANE (PR*PR)         // 3364

// ws layout (floats for wsf): [8..43] = 36 per-block |w| partials (plain
// stores, no init needed); [64..319] = F_SUM; [320..575] = F_SQ (zeroed by
// pack_all block 428, which completes before conv via stream ordering).
#define F_WPART 8
#define F_SUM   64
#define F_SQ    320
#define WPK_OFF  4096                     // i8 wpk[kc=36][co=256][64]  (A repack)
#define WPK_BYTES WELEMS                  // 589824
#define ACT_OFF  (WPK_OFF + WPK_BYTES)    // 593920 (16B aligned)
#define ACT_BYTES (Bn*PPLANE*Cn)          // 27553792

typedef int v4i __attribute__((ext_vector_type(4)));

#define GLOBAL_AS __attribute__((address_space(1)))
#define LDS_AS    __attribute__((address_space(3)))

// ---------------------------------------------------------------------------
// Fused packing kernel, round-10 rewrite of the activation path.
// Blocks 0..391   : activation pack, thread = (pixel-quad, channel-quarter).
//   Loads are float4 (4 consecutive pixels of one channel): 64 loads/thread
//   instead of 256 scalars -> 4x memory-level parallelism (the old kernel ran
//   ~0.8 TB/s, latency-bound on 256 serial dword loads/thread).
//   Lane-consecutive quads => each wave load instr covers 1KB contiguous.
// Blocks 392..427 : weight repack (verified rounds 3-9, unchanged).
// Blocks 428..456 : halo zeroing (7296 x 256B) + BN-stats zero-init.
__global__ void pack_all(const float* __restrict__ x,
                         const float* __restrict__ w,
                         float* __restrict__ wsf,
                         uint8_t* __restrict__ wpk,
                         uint8_t* __restrict__ act) {
    if (blockIdx.x < 392) {
        int u  = blockIdx.x * 256 + threadIdx.x;   // 0..100351
        int s4 = u / 25088;                        // channel quarter 0..3
        int q  = u - s4 * 25088;                   // pixel quad 0..25087
        int b  = q / 784;
        int pq = q - b * 784;
        int y  = pq / 14;
        int xs = (pq - y * 14) * 4;                // first of 4 pixels (same row)
        int p0 = y * 56 + xs;

        const float* xpb = x + ((size_t)b * Cn + s4 * 64) * HWn + p0;

        uint32_t a[4][16];                         // 4 pixels x 64 channels
        #pragma unroll
        for (int px = 0; px < 4; px++)
            #pragma unroll
            for (int wd = 0; wd < 16; wd++) a[px][wd] = 0;

        #pragma unroll
        for (int m = 0; m < 64; m++) {
            float4 v = *(const float4*)(xpb + (size_t)m * HWn);
            uint32_t s0 = __float_as_uint(v.x) >> 31;
            uint32_t s1 = __float_as_uint(v.y) >> 31;
            uint32_t s2 = __float_as_uint(v.z) >> 31;
            uint32_t s3 = __float_as_uint(v.w) >> 31;
            int wd = m >> 2, sh = (m & 3) * 8;
            a[0][wd] |= (s0 ? 0xFFu : 0x01u) << sh;
            a[1][wd] |= (s1 ? 0xFFu : 0x01u) << sh;
            a[2][wd] |= (s2 ? 0xFFu : 0x01u) << sh;
            a[3][wd] |= (s3 ? 0xFFu : 0x01u) << sh;
        }

        #pragma unroll
        for (int px = 0; px < 4; px++) {
            int key = (xs + px + 1) & 15;
            uint32_t* dst = (uint32_t*)(act +
                ((size_t)(b * PR + (y + 1)) * PR + (xs + px + 1)) * 256);
            #pragma unroll
            for (int wd = 0; wd < 4; wd++) {
                int slot = s4 * 4 + wd;
                *(uint4*)(dst + (size_t)(((slot ^ key) * 4))) =
                    make_uint4(a[px][wd * 4 + 0], a[px][wd * 4 + 1],
                               a[px][wd * 4 + 2], a[px][wd * 4 + 3]);
            }
        }
    } else if (blockIdx.x < 428) {
        int u = (blockIdx.x - 392) * 256 + threadIdx.x;   // 36*256 = 9216
        int co = u / 36;
        int kc = u - co * 36;
        int t  = kc >> 2;          // tap
        int s  = kc & 3;           // 64-ci chunk
        const float* wp = w + (size_t)co * 2304 + t;      // OIHW
        uint32_t* dst = (uint32_t*)(wpk + ((size_t)kc * 256 + co) * 64);
        float sabs = 0.0f;
        #pragma unroll
        for (int cw = 0; cw < 16; cw++) {
            uint32_t r = 0;
            #pragma unroll
            for (int j = 0; j < 4; j++) {
                int ci = s * 64 + cw * 4 + j;
                float wv = wp[(size_t)ci * 9];
                sabs += fminf(fabsf(wv), 1.0f);
                r |= ((__float_as_uint(wv) >> 31) ? 0xFFu : 0x01u) << (j * 8);
            }
            dst[cw] = r;
        }
        #pragma unroll
        for (int off = 32; off; off >>= 1) sabs += __shfl_down(sabs, off);
        __shared__ float sh[4];
        if ((threadIdx.x & 63) == 0) sh[threadIdx.x >> 6] = sabs;
        __syncthreads();
        if (threadIdx.x == 0)   // plain store: no atomic, no init required
            wsf[F_WPART + (blockIdx.x - 392)] = sh[0] + sh[1] + sh[2] + sh[3];
    } else {
        // --- BN-stats zero-init (one block's worth) ---
        if (blockIdx.x == 428) {
            wsf[F_SUM + threadIdx.x] = 0.0f;          // 64..319
            wsf[F_SQ  + threadIdx.x] = 0.0f;          // 320..575
        }
        // --- halo zeroing: 32 batches * 228 border pixels = 7296 blocks ---
        int hv = (blockIdx.x - 428) * 256 + threadIdx.x;
        if (hv < 7296) {
            int b = hv / 228;
            int r = hv - b * 228;
            int y, xx;
            if (r < 58)       { y = 0;  xx = r; }
            else if (r < 116) { y = 57; xx = r - 58; }
            else { int r2 = r - 116; y = 1 + (r2 >> 1); xx = (r2 & 1) * 57; }
            uint4* d = (uint4*)(act + ((size_t)(b * PR + y) * PR + xx) * 256);
            uint4 z = make_uint4(0, 0, 0, 0);
            #pragma unroll
            for (int i = 0; i < 16; i++) d[i] = z;
        }
    }
}

// ---------------------------------------------------------------------------
// Binary conv as implicit GEMM on the i8 matrix pipe, LDS-staged B.
// FROZEN at the round-8 local optimum (126.8us): 4 waves, wave tile 64co x
// 112px, depth-4 A-pipeline af0..af3, single bf, runtime t-loop, async
// global_load_lds staging. Rounds 5/6/9 proved: deeper B-pipelining, and any
// occupancy-via-smaller-tile trade, regress (spill or LDS-traffic doubling).
__global__ __launch_bounds__(256, 2) void conv_mfma(
    const uint8_t* __restrict__ act, const uint8_t* __restrict__ wpk,
    const float* __restrict__ x, float* __restrict__ wsf,
    float* __restrict__ out) {
    __shared__ uint4 ldsv[3712];              // 59392 B = 58 chunks of 1KB
    uint8_t* lds = (uint8_t*)ldsv;

    const int tid  = threadIdx.x;
    const int lane = tid & 63;
    const int wid  = tid >> 6;                // 0..3
    const int l15  = lane & 15;
    const int l4   = lane >> 4;               // 0..3

    const int bx = blockIdx.x;                // 0..895
    const int b  = bx / 28;
    const int y0 = (bx - b * 28) * 2;         // first output image row

    // Stage padded rows y0..y0+3 via async global->LDS DMA: 58 x 1KB chunks,
    // wave w issues chunks {w, w+4, ...} back-to-back, no waits here.
    {
        const uint8_t* src = act + ((size_t)b * PR + y0) * PR * 256;
        #pragma unroll
        for (int j = 0; j < 15; j++) {
            int c = wid + j * 4;               // wave-uniform
            if (c < 58) {
                __builtin_amdgcn_global_load_lds(
                    (const GLOBAL_AS uint32_t*)(const void*)(src + c * 1024 + lane * 16),
                    (LDS_AS uint32_t*)(void*)(lds + c * 1024),
                    16, 0, 0);
            }
        }
    }

    // A-fragment lane base (co = wid*64 + mi*16 + l15, bytes l4*16)
    const uint8_t* abase = wpk + (wid * 64 + l15) * 64 + l4 * 16;

    // Pipeline prologue: fill the 4 A-buffers with kc = 0..3.
    v4i af0[4], af1[4], af2[4], af3[4];
    #pragma unroll
    for (int mi = 0; mi < 4; mi++) {
        af0[mi] = *(const v4i*)(abase + (size_t)0 * 16384 + mi * 1024);
        af1[mi] = *(const v4i*)(abase + (size_t)1 * 16384 + mi * 1024);
        af2[mi] = *(const v4i*)(abase + (size_t)2 * 16384 + mi * 1024);
        af3[mi] = *(const v4i*)(abase + (size_t)3 * 16384 + mi * 1024);
    }

    // Tap-walking state for t=0 (dh=-1, dw=-1): window corner (r_, c_) local.
    int pixb[7], key[7];
    #pragma unroll
    for (int ni = 0; ni < 7; ni++) {
        int n  = ni * 16 + l15;
        int r_ = n / 56;
        int c_ = n - r_ * 56;
        pixb[ni] = (r_ * 58 + c_) * 256;
        key[ni]  = c_ & 15;
    }

    __syncthreads();   // drains vmcnt(0): LDS-DMA chunks + af loads all ready

    v4i acc[4][7] = {};

// STEP: load bf for sub-step S, run 28 MFMAs on the resident AF buffer,
// then reload AF with K-chunk KCN (distance-4 ahead, clamped tail).
#define STEP(S, AF)                                                            \
    {                                                                          \
        v4i bf[7];                                                             \
        _Pragma("unroll")                                                      \
        for (int ni = 0; ni < 7; ni++)                                         \
            bf[ni] = *(const v4i*)(lds + pixb[ni] +                            \
                                   ((((S) * 4 + l4) ^ key[ni]) << 4));         \
        _Pragma("unroll")                                                      \
        for (int ni = 0; ni < 7; ni++) {                                       \
            _Pragma("unroll")                                                  \
            for (int mi = 0; mi < 4; mi++)                                     \
                acc[mi][ni] = __builtin_amdgcn_mfma_i32_16x16x64_i8(           \
                    AF[mi], bf[ni], acc[mi][ni], 0, 0, 0);                     \
        }                                                                      \
        {                                                                      \
            int kcn = t4 + (S) + 4;                                            \
            kcn = kcn > 35 ? 35 : kcn;   /* tail: redundant reload, unused */  \
            const uint8_t* ap = abase + (size_t)kcn * 16384;                   \
            _Pragma("unroll")                                                  \
            for (int mi = 0; mi < 4; mi++)                                     \
                AF[mi] = *(const v4i*)(ap + mi * 1024);                        \
        }                                                                      \
    }

    #pragma unroll 1
    for (int t = 0; t < 9; t++) {
        const int t4 = t * 4;
        STEP(0, af0)
        STEP(1, af1)
        STEP(2, af2)
        STEP(3, af3)
        // Tap-walk t -> t+1: dw cycles -1,0,1 (ddw=+1, dtoff=+256), wrapping
        // at t=2,5 (ddw=-2, dtoff=(58-2)*256); t=8 is the end (no-op).
        const int wrap  = (t == 2 || t == 5);
        const int dtoff = (t == 8) ? 0 : (wrap ? 56 * 256 : 256);
        const int ddw   = (t == 8) ? 0 : (wrap ? -2 : 1);
        #pragma unroll
        for (int ni = 0; ni < 7; ni++) {
            pixb[ni] += dtoff;
            key[ni]   = (key[ni] + ddw) & 15;
        }
    }
#undef STEP

    // mean(|clip(w)|) from the 36 per-block partials (uniform, cheap).
    float wabs = 0.0f;
    #pragma unroll
    for (int j = 0; j < 36; j++) wabs += wsf[F_WPART + j];
    const float mv = wabs * (1.0f / (float)WELEMS);

    const int co_w = wid * 64;
    const int pbase = b * (Cn * HWn) + y0 * 56;

    // Epilogue: scale + shortcut + store + per-channel partial stats.
    float ssum[4][4] = {}, ssq[4][4] = {};
    #pragma unroll
    for (int mi = 0; mi < 4; mi++) {
        #pragma unroll
        for (int ni = 0; ni < 7; ni++) {
            v4i a = acc[mi][ni];
            #pragma unroll
            for (int q = 0; q < 4; q++) {
                int co = co_w + mi * 16 + l4 * 4 + q;
                size_t idx = (size_t)pbase + (size_t)co * HWn + (ni * 16 + l15);
                float val = fmaf(mv, (float)a[q], x[idx]);
                out[idx] = val;
                ssum[mi][q] += val;
                ssq[mi][q]  += val * val;
            }
        }
    }
    // Reduce across the 16 lanes (l15) sharing each channel, then atomics.
    #pragma unroll
    for (int mi = 0; mi < 4; mi++) {
        #pragma unroll
        for (int q = 0; q < 4; q++) {
            float s = ssum[mi][q], sq = ssq[mi][q];
            #pragma unroll
            for (int off = 1; off < 16; off <<= 1) {
                s  += __shfl_xor(s, off);
                sq += __shfl_xor(sq, off);
            }
            if (l15 == 0) {
                int co = co_w + mi * 16 + l4 * 4 + q;
                atomicAdd(&wsf[F_SUM + co], s);
                atomicAdd(&wsf[F_SQ  + co], sq);
            }
        }
    }
}

// ---------------------------------------------------------------------------
// BN finalize (per-plane, from fused stats) + normalize + ReLU, in place.
__global__ void epilogue_kernel(float* __restrict__ out,
                                const float* __restrict__ wsf,
                                const float* __restrict__ g,
                                const float* __restrict__ bt) {
    int plane = blockIdx.x;   // b*256 + c
    int c = plane & 255;
    const float n = (float)(Bn * HWn);
    float mean = wsf[F_SUM + c] / n;
    float var  = wsf[F_SQ + c] / n - mean * mean;
    float sc = g[c] * rsqrtf(var + EPSv);
    float sh = bt[c] - mean * sc;
    float4* o4 = (float4*)(out + (size_t)plane * HWn);
    for (int i = threadIdx.x; i < HWn / 4; i += 256) {
        float4 v = o4[i];
        v.x = fmaxf(fmaf(v.x, sc, sh), 0.0f);
        v.y = fmaxf(fmaf(v.y, sc, sh), 0.0f);
        v.z = fmaxf(fmaf(v.z, sc, sh), 0.0f);
        v.w = fmaxf(fmaf(v.w, sc, sh), 0.0f);
        o4[i] = v;
    }
}

// ---------------------------------------------------------------------------
extern "C" void kernel_launch(void* const* d_in, const int* in_sizes, int n_in,
                              void* d_out, int out_size, void* d_ws, size_t ws_size,
                              hipStream_t stream) {
    const float* x     = (const float*)d_in[0];
    const float* w     = (const float*)d_in[1];
    const float* gamma = (const float*)d_in[2];
    const float* beta  = (const float*)d_in[3];
    float* out = (float*)d_out;

    float*   wsf = (float*)d_ws;
    uint8_t* wpk = (uint8_t*)d_ws + WPK_OFF;
    uint8_t* act = (uint8_t*)d_ws + ACT_OFF;

    pack_all<<<dim3(457), dim3(256), 0, stream>>>(x, w, wsf, wpk, act);
    conv_mfma<<<dim3(896), dim3(256), 0, stream>>>(act, wpk, x, wsf, out);
    epilogue_kernel<<<dim3(Bn * Cn), dim3(256), 0, stream>>>(out, wsf, gamma, beta);
}

// Round 11
// 349.228 us; speedup vs baseline: 1.3743x; 1.1370x over previous
//
#include <hip/hip_runtime.h>
#include <cstdint>

// Problem constants
#define Bn   32
#define Cn   256
#define Hn   56
#define Wn   56
#define HWn  (Hn*Wn)           // 3136
#define NPIX (Bn*HWn)          // 100352
#define WELEMS (Cn*Cn*9)       // 589824
#define EPSv 1e-5f

// padded channels-last activation plane: [b][58 rows][58 cols][256 ci] i8
// per-pixel 256B block stored XOR-swizzled: 16B slot s lives at s ^ (padded_col & 15)
#define PR   58
#define PPLANE (PR*PR)         // 3364

// ws layout (floats for wsf): [8..43] = 36 per-block |w| partials (plain
// stores, no init needed); [64..319] = F_SUM; [320..575] = F_SQ (zeroed by
// pack_all blocks 0/1, which complete before conv via stream ordering).
#define F_WPART 8
#define F_SUM   64
#define F_SQ    320
#define WPK_OFF  4096                     // i8 wpk[kc=36][co=256][64]  (A repack)
#define WPK_BYTES WELEMS                  // 589824
#define ACT_OFF  (WPK_OFF + WPK_BYTES)    // 593920 (16B aligned)
#define ACT_BYTES (Bn*PPLANE*Cn)          // 27553792

typedef int v4i __attribute__((ext_vector_type(4)));

#define GLOBAL_AS __attribute__((address_space(1)))
#define LDS_AS    __attribute__((address_space(3)))

// ---------------------------------------------------------------------------
// Fused packing kernel — EXACT round-8 version (verified best: pack not a
// bottleneck; round-10's "improved" pack regressed via L2 partial-line
// assembly and was reverted).
__global__ void pack_all(const float* __restrict__ x,
                         const float* __restrict__ w,
                         float* __restrict__ wsf,
                         uint8_t* __restrict__ wpk,
                         uint8_t* __restrict__ act) {
    if (blockIdx.x < 392) {
        // --- BN-stats zero-init (replaces the memset dispatch) ---
        if (blockIdx.x < 2)
            wsf[F_SUM + blockIdx.x * 256 + threadIdx.x] = 0.0f;

        int v = blockIdx.x * 256 + threadIdx.x;   // 0..100351
        // --- halo zeroing: 32 batches * 228 border pixels = 7296 ---
        if (v < 7296) {
            int b = v / 228;
            int r = v - b * 228;
            int y, xx;
            if (r < 58)       { y = 0;  xx = r; }
            else if (r < 116) { y = 57; xx = r - 58; }
            else { int r2 = r - 116; y = 1 + (r2 >> 1); xx = (r2 & 1) * 57; }
            uint4* d = (uint4*)(act + ((size_t)(b * PR + y) * PR + xx) * 256);
            uint4 z = make_uint4(0, 0, 0, 0);
            #pragma unroll
            for (int i = 0; i < 16; i++) d[i] = z;
        }
        // --- interior pack with per-pixel XOR swizzle ---
        int b = v / HWn;
        int p = v - b * HWn;
        int y = p / Wn;
        int xx = p - y * Wn;
        const float* xp = x + (size_t)b * Cn * HWn + p;
        int key = (xx + 1) & 15;
        uint32_t* dst = (uint32_t*)(act + ((size_t)(b * PR + (y + 1)) * PR + (xx + 1)) * 256);
        #pragma unroll
        for (int slot = 0; slot < 16; slot++) {
            uint32_t rr[4];
            #pragma unroll
            for (int cw = 0; cw < 4; cw++) {
                uint32_t r = 0;
                #pragma unroll
                for (int j = 0; j < 4; j++) {
                    uint32_t sgn = __float_as_uint(xp[(size_t)(slot * 16 + cw * 4 + j) * HWn]) >> 31;
                    r |= (sgn ? 0xFFu : 0x01u) << (j * 8);
                }
                rr[cw] = r;
            }
            *(uint4*)(dst + (size_t)((slot ^ key) * 4)) = make_uint4(rr[0], rr[1], rr[2], rr[3]);
        }
    } else {
        int u = (blockIdx.x - 392) * 256 + threadIdx.x;   // 36*256 = 9216
        int co = u / 36;
        int kc = u - co * 36;
        int t  = kc >> 2;          // tap
        int s  = kc & 3;           // 64-ci chunk
        const float* wp = w + (size_t)co * 2304 + t;      // OIHW
        uint32_t* dst = (uint32_t*)(wpk + ((size_t)kc * 256 + co) * 64);
        float sabs = 0.0f;
        #pragma unroll
        for (int cw = 0; cw < 16; cw++) {
            uint32_t r = 0;
            #pragma unroll
            for (int j = 0; j < 4; j++) {
                int ci = s * 64 + cw * 4 + j;
                float wv = wp[(size_t)ci * 9];
                sabs += fminf(fabsf(wv), 1.0f);
                r |= ((__float_as_uint(wv) >> 31) ? 0xFFu : 0x01u) << (j * 8);
            }
            dst[cw] = r;
        }
        #pragma unroll
        for (int off = 32; off; off >>= 1) sabs += __shfl_down(sabs, off);
        __shared__ float sh[4];
        if ((threadIdx.x & 63) == 0) sh[threadIdx.x >> 6] = sabs;
        __syncthreads();
        if (threadIdx.x == 0)   // plain store: no atomic, no init required
            wsf[F_WPART + (blockIdx.x - 392)] = sh[0] + sh[1] + sh[2] + sh[3];
    }
}

// ---------------------------------------------------------------------------
// Binary conv as implicit GEMM on the i8 matrix pipe, LDS-staged B.
// Round-8 structure (verified local optimum: 4 waves, wave tile 64co x 112px,
// depth-4 A-pipeline, single bf, runtime t-loop, global_load_lds staging)
// plus two independent additions:
//  * T1 XCD-aware block swizzle: 896 blocks, 896%8==0 -> XCD k gets tiles
//    [k*112,(k+1)*112) = 4 complete batches; their act (3.4MB) + wpk (590KB)
//    fit one XCD's 4MB L2, and adjacent row-pair blocks share halo rows.
//  * T5 s_setprio(1) around the MFMA cluster: no intra-K-loop barriers here,
//    so resident waves sit at independent phases (the regime where setprio
//    measured +4-7%, not the barrier-locked null case).
__global__ __launch_bounds__(256, 2) void conv_mfma(
    const uint8_t* __restrict__ act, const uint8_t* __restrict__ wpk,
    const float* __restrict__ x, float* __restrict__ wsf,
    float* __restrict__ out) {
    __shared__ uint4 ldsv[3712];              // 59392 B = 58 chunks of 1KB
    uint8_t* lds = (uint8_t*)ldsv;

    const int tid  = threadIdx.x;
    const int lane = tid & 63;
    const int wid  = tid >> 6;                // 0..3
    const int l15  = lane & 15;
    const int l4   = lane >> 4;               // 0..3

    // XCD-aware swizzle: dispatch round-robins XCDs by blockIdx, so give
    // XCD k the contiguous tile range [k*112, (k+1)*112).
    const int bxr = blockIdx.x;               // 0..895
    const int bx  = (bxr & 7) * 112 + (bxr >> 3);
    const int b   = bx / 28;
    const int y0  = (bx - b * 28) * 2;        // first output image row

    // Stage padded rows y0..y0+3 via async global->LDS DMA: 58 x 1KB chunks,
    // wave w issues chunks {w, w+4, ...} back-to-back, no waits here.
    {
        const uint8_t* src = act + ((size_t)b * PR + y0) * PR * 256;
        #pragma unroll
        for (int j = 0; j < 15; j++) {
            int c = wid + j * 4;               // wave-uniform
            if (c < 58) {
                __builtin_amdgcn_global_load_lds(
                    (const GLOBAL_AS uint32_t*)(const void*)(src + c * 1024 + lane * 16),
                    (LDS_AS uint32_t*)(void*)(lds + c * 1024),
                    16, 0, 0);
            }
        }
    }

    // A-fragment lane base (co = wid*64 + mi*16 + l15, bytes l4*16)
    const uint8_t* abase = wpk + (wid * 64 + l15) * 64 + l4 * 16;

    // Pipeline prologue: fill the 4 A-buffers with kc = 0..3.
    v4i af0[4], af1[4], af2[4], af3[4];
    #pragma unroll
    for (int mi = 0; mi < 4; mi++) {
        af0[mi] = *(const v4i*)(abase + (size_t)0 * 16384 + mi * 1024);
        af1[mi] = *(const v4i*)(abase + (size_t)1 * 16384 + mi * 1024);
        af2[mi] = *(const v4i*)(abase + (size_t)2 * 16384 + mi * 1024);
        af3[mi] = *(const v4i*)(abase + (size_t)3 * 16384 + mi * 1024);
    }

    // Tap-walking state for t=0 (dh=-1, dw=-1): window corner (r_, c_) local.
    int pixb[7], key[7];
    #pragma unroll
    for (int ni = 0; ni < 7; ni++) {
        int n  = ni * 16 + l15;
        int r_ = n / 56;
        int c_ = n - r_ * 56;
        pixb[ni] = (r_ * 58 + c_) * 256;
        key[ni]  = c_ & 15;
    }

    __syncthreads();   // drains vmcnt(0): LDS-DMA chunks + af loads all ready

    v4i acc[4][7] = {};

// STEP: load bf for sub-step S, run 28 MFMAs (priority-boosted) on the
// resident AF buffer, then reload AF with K-chunk KCN (distance-4, clamped).
#define STEP(S, AF)                                                            \
    {                                                                          \
        v4i bf[7];                                                             \
        _Pragma("unroll")                                                      \
        for (int ni = 0; ni < 7; ni++)                                         \
            bf[ni] = *(const v4i*)(lds + pixb[ni] +                            \
                                   ((((S) * 4 + l4) ^ key[ni]) << 4));         \
        __builtin_amdgcn_s_setprio(1);                                         \
        _Pragma("unroll")                                                      \
        for (int ni = 0; ni < 7; ni++) {                                       \
            _Pragma("unroll")                                                  \
            for (int mi = 0; mi < 4; mi++)                                     \
                acc[mi][ni] = __builtin_amdgcn_mfma_i32_16x16x64_i8(           \
                    AF[mi], bf[ni], acc[mi][ni], 0, 0, 0);                     \
        }                                                                      \
        __builtin_amdgcn_s_setprio(0);                                         \
        {                                                                      \
            int kcn = t4 + (S) + 4;                                            \
            kcn = kcn > 35 ? 35 : kcn;   /* tail: redundant reload, unused */  \
            const uint8_t* ap = abase + (size_t)kcn * 16384;                   \
            _Pragma("unroll")                                                  \
            for (int mi = 0; mi < 4; mi++)                                     \
                AF[mi] = *(const v4i*)(ap + mi * 1024);                        \
        }                                                                      \
    }

    #pragma unroll 1
    for (int t = 0; t < 9; t++) {
        const int t4 = t * 4;
        STEP(0, af0)
        STEP(1, af1)
        STEP(2, af2)
        STEP(3, af3)
        // Tap-walk t -> t+1: dw cycles -1,0,1 (ddw=+1, dtoff=+256), wrapping
        // at t=2,5 (ddw=-2, dtoff=(58-2)*256); t=8 is the end (no-op).
        const int wrap  = (t == 2 || t == 5);
        const int dtoff = (t == 8) ? 0 : (wrap ? 56 * 256 : 256);
        const int ddw   = (t == 8) ? 0 : (wrap ? -2 : 1);
        #pragma unroll
        for (int ni = 0; ni < 7; ni++) {
            pixb[ni] += dtoff;
            key[ni]   = (key[ni] + ddw) & 15;
        }
    }
#undef STEP

    // mean(|clip(w)|) from the 36 per-block partials (uniform, cheap).
    float wabs = 0.0f;
    #pragma unroll
    for (int j = 0; j < 36; j++) wabs += wsf[F_WPART + j];
    const float mv = wabs * (1.0f / (float)WELEMS);

    const int co_w = wid * 64;
    const int pbase = b * (Cn * HWn) + y0 * 56;

    // Epilogue: scale + shortcut + store + per-channel partial stats.
    float ssum[4][4] = {}, ssq[4][4] = {};
    #pragma unroll
    for (int mi = 0; mi < 4; mi++) {
        #pragma unroll
        for (int ni = 0; ni < 7; ni++) {
            v4i a = acc[mi][ni];
            #pragma unroll
            for (int q = 0; q < 4; q++) {
                int co = co_w + mi * 16 + l4 * 4 + q;
                size_t idx = (size_t)pbase + (size_t)co * HWn + (ni * 16 + l15);
                float val = fmaf(mv, (float)a[q], x[idx]);
                out[idx] = val;
                ssum[mi][q] += val;
                ssq[mi][q]  += val * val;
            }
        }
    }
    // Reduce across the 16 lanes (l15) sharing each channel, then atomics.
    #pragma unroll
    for (int mi = 0; mi < 4; mi++) {
        #pragma unroll
        for (int q = 0; q < 4; q++) {
            float s = ssum[mi][q], sq = ssq[mi][q];
            #pragma unroll
            for (int off = 1; off < 16; off <<= 1) {
                s  += __shfl_xor(s, off);
                sq += __shfl_xor(sq, off);
            }
            if (l15 == 0) {
                int co = co_w + mi * 16 + l4 * 4 + q;
                atomicAdd(&wsf[F_SUM + co], s);
                atomicAdd(&wsf[F_SQ  + co], sq);
            }
        }
    }
}

// ---------------------------------------------------------------------------
// BN finalize (per-plane, from fused stats) + normalize + ReLU, in place.
__global__ void epilogue_kernel(float* __restrict__ out,
                                const float* __restrict__ wsf,
                                const float* __restrict__ g,
                                const float* __restrict__ bt) {
    int plane = blockIdx.x;   // b*256 + c
    int c = plane & 255;
    const float n = (float)(Bn * HWn);
    float mean = wsf[F_SUM + c] / n;
    float var  = wsf[F_SQ + c] / n - mean * mean;
    float sc = g[c] * rsqrtf(var + EPSv);
    float sh = bt[c] - mean * sc;
    float4* o4 = (float4*)(out + (size_t)plane * HWn);
    for (int i = threadIdx.x; i < HWn / 4; i += 256) {
        float4 v = o4[i];
        v.x = fmaxf(fmaf(v.x, sc, sh), 0.0f);
        v.y = fmaxf(fmaf(v.y, sc, sh), 0.0f);
        v.z = fmaxf(fmaf(v.z, sc, sh), 0.0f);
        v.w = fmaxf(fmaf(v.w, sc, sh), 0.0f);
        o4[i] = v;
    }
}

// ---------------------------------------------------------------------------
extern "C" void kernel_launch(void* const* d_in, const int* in_sizes, int n_in,
                              void* d_out, int out_size, void* d_ws, size_t ws_size,
                              hipStream_t stream) {
    const float* x     = (const float*)d_in[0];
    const float* w     = (const float*)d_in[1];
    const float* gamma = (const float*)d_in[2];
    const float* beta  = (const float*)d_in[3];
    float* out = (float*)d_out;

    float*   wsf = (float*)d_ws;
    uint8_t* wpk = (uint8_t*)d_ws + WPK_OFF;
    uint8_t* act = (uint8_t*)d_ws + ACT_OFF;

    pack_all<<<dim3(428), dim3(256), 0, stream>>>(x, w, wsf, wpk, act);
    conv_mfma<<<dim3(896), dim3(256), 0, stream>>>(act, wpk, x, wsf, out);
    epilogue_kernel<<<dim3(Bn * Cn), dim3(256), 0, stream>>>(out, wsf, gamma, beta);
}

// Round 12
// 348.621 us; speedup vs baseline: 1.3767x; 1.0017x over previous
//
#include <hip/hip_runtime.h>
#include <cstdint>

// Problem constants
#define Bn   32
#define Cn   256
#define Hn   56
#define Wn   56
#define HWn  (Hn*Wn)           // 3136
#define NPIX (Bn*HWn)          // 100352
#define WELEMS (Cn*Cn*9)       // 589824
#define EPSv 1e-5f

// padded channels-last activation plane: [b][58 rows][58 cols][256 ci] i8
// per-pixel 256B block stored XOR-swizzled: 16B slot s lives at s ^ (padded_col & 15)
#define PR   58
#define PPLANE (PR*PR)         // 3364

// ws layout (floats for wsf): [8..80) = 72 per-block |w| partials (plain
// stores, no init needed); [128..384) = F_SUM; [384..640) = F_SQ (zeroed by
// pack_all tail blocks, which complete before conv via stream ordering).
#define F_WPART 8
#define F_SUM   128
#define F_SQ    384
#define WPK_OFF  4096              // i8 wpk[kc=36(+4 pad)][co=256][64]
#define WPK_SLOTS 40               // 4 pad slots: A-prefetch reads kc<=39 (garbage, unused)
#define ACT_OFF  (WPK_OFF + WPK_SLOTS*16384)   // 659456 (16B aligned)
#define ACT_BYTES (Bn*PPLANE*Cn)   // 27553792

typedef int v4i __attribute__((ext_vector_type(4)));

#define GLOBAL_AS __attribute__((address_space(1)))
#define LDS_AS    __attribute__((address_space(3)))

// ---------------------------------------------------------------------------
// Fused packing kernel, round-12 REGRID (bodies unchanged from verified R8):
// R8 ran act-pack as 392x256 = 1.53 blocks/CU -> half the GPU at 1 wave/SIMD,
// latency-exposed on the 98MB read. Now 128-thread blocks:
//   [0,784)    act pack (2 waves/block, ~6 waves/CU, balanced)
//   [784,856)  weight repack -> 72 partials
//   [856,913)  halo zeroing (7296 border pixels)
//   [913,917)  BN-stats zero-init (512 floats)
__global__ void pack_all(const float* __restrict__ x,
                         const float* __restrict__ w,
                         float* __restrict__ wsf,
                         uint8_t* __restrict__ wpk,
                         uint8_t* __restrict__ act) {
    if (blockIdx.x < 784) {
        int v = blockIdx.x * 128 + threadIdx.x;   // 0..100351
        int b = v / HWn;
        int p = v - b * HWn;
        int y = p / Wn;
        int xx = p - y * Wn;
        const float* xp = x + (size_t)b * Cn * HWn + p;
        int key = (xx + 1) & 15;
        uint32_t* dst = (uint32_t*)(act + ((size_t)(b * PR + (y + 1)) * PR + (xx + 1)) * 256);
        #pragma unroll
        for (int slot = 0; slot < 16; slot++) {
            uint32_t rr[4];
            #pragma unroll
            for (int cw = 0; cw < 4; cw++) {
                uint32_t r = 0;
                #pragma unroll
                for (int j = 0; j < 4; j++) {
                    uint32_t sgn = __float_as_uint(xp[(size_t)(slot * 16 + cw * 4 + j) * HWn]) >> 31;
                    r |= (sgn ? 0xFFu : 0x01u) << (j * 8);
                }
                rr[cw] = r;
            }
            *(uint4*)(dst + (size_t)((slot ^ key) * 4)) = make_uint4(rr[0], rr[1], rr[2], rr[3]);
        }
    } else if (blockIdx.x < 856) {
        int u = (blockIdx.x - 784) * 128 + threadIdx.x;   // 72*128 = 9216
        int co = u / 36;
        int kc = u - co * 36;
        int t  = kc >> 2;          // tap
        int s  = kc & 3;           // 64-ci chunk
        const float* wp = w + (size_t)co * 2304 + t;      // OIHW
        uint32_t* dst = (uint32_t*)(wpk + ((size_t)kc * 256 + co) * 64);
        float sabs = 0.0f;
        #pragma unroll
        for (int cw = 0; cw < 16; cw++) {
            uint32_t r = 0;
            #pragma unroll
            for (int j = 0; j < 4; j++) {
                int ci = s * 64 + cw * 4 + j;
                float wv = wp[(size_t)ci * 9];
                sabs += fminf(fabsf(wv), 1.0f);
                r |= ((__float_as_uint(wv) >> 31) ? 0xFFu : 0x01u) << (j * 8);
            }
            dst[cw] = r;
        }
        #pragma unroll
        for (int off = 32; off; off >>= 1) sabs += __shfl_down(sabs, off);
        __shared__ float sh[2];
        if ((threadIdx.x & 63) == 0) sh[threadIdx.x >> 6] = sabs;
        __syncthreads();
        if (threadIdx.x == 0)   // plain store: no atomic, no init required
            wsf[F_WPART + (blockIdx.x - 784)] = sh[0] + sh[1];
    } else if (blockIdx.x < 913) {
        // --- halo zeroing: 32 batches * 228 border pixels = 7296 ---
        int hv = (blockIdx.x - 856) * 128 + threadIdx.x;
        int b = hv / 228;
        int r = hv - b * 228;
        int y, xx;
        if (r < 58)       { y = 0;  xx = r; }
        else if (r < 116) { y = 57; xx = r - 58; }
        else { int r2 = r - 116; y = 1 + (r2 >> 1); xx = (r2 & 1) * 57; }
        uint4* d = (uint4*)(act + ((size_t)(b * PR + y) * PR + xx) * 256);
        uint4 z = make_uint4(0, 0, 0, 0);
        #pragma unroll
        for (int i = 0; i < 16; i++) d[i] = z;
    } else {
        // --- BN-stats zero-init: 512 floats at F_SUM ---
        int idx = (blockIdx.x - 913) * 128 + threadIdx.x;
        wsf[F_SUM + idx] = 0.0f;
    }
}

// ---------------------------------------------------------------------------
// Binary conv as implicit GEMM on the i8 matrix pipe, LDS-staged B.
// FROZEN structure (R8/R11 local optimum, 126.8us): 4 waves, wave tile
// 64co x 112px, depth-4 A-pipeline, single bf, runtime t-loop,
// global_load_lds staging, T1 XCD swizzle (FETCH -21%), T5 setprio.
// Round-12 micro: wpk padded to 40 kc-slots -> A-prefetch address is affine
// (no clamp cmp/select; tail reads land in pad, loaded but never consumed).
__global__ __launch_bounds__(256, 2) void conv_mfma(
    const uint8_t* __restrict__ act, const uint8_t* __restrict__ wpk,
    const float* __restrict__ x, float* __restrict__ wsf,
    float* __restrict__ out) {
    __shared__ uint4 ldsv[3712];              // 59392 B = 58 chunks of 1KB
    uint8_t* lds = (uint8_t*)ldsv;

    const int tid  = threadIdx.x;
    const int lane = tid & 63;
    const int wid  = tid >> 6;                // 0..3
    const int l15  = lane & 15;
    const int l4   = lane >> 4;               // 0..3

    // XCD-aware swizzle: XCD k gets the contiguous tile range [k*112,(k+1)*112).
    const int bxr = blockIdx.x;               // 0..895
    const int bx  = (bxr & 7) * 112 + (bxr >> 3);
    const int b   = bx / 28;
    const int y0  = (bx - b * 28) * 2;        // first output image row

    // Stage padded rows y0..y0+3 via async global->LDS DMA: 58 x 1KB chunks.
    {
        const uint8_t* src = act + ((size_t)b * PR + y0) * PR * 256;
        #pragma unroll
        for (int j = 0; j < 15; j++) {
            int c = wid + j * 4;               // wave-uniform
            if (c < 58) {
                __builtin_amdgcn_global_load_lds(
                    (const GLOBAL_AS uint32_t*)(const void*)(src + c * 1024 + lane * 16),
                    (LDS_AS uint32_t*)(void*)(lds + c * 1024),
                    16, 0, 0);
            }
        }
    }

    // A-fragment lane base (co = wid*64 + mi*16 + l15, bytes l4*16)
    const uint8_t* abase = wpk + (wid * 64 + l15) * 64 + l4 * 16;

    // Pipeline prologue: fill the 4 A-buffers with kc = 0..3.
    v4i af0[4], af1[4], af2[4], af3[4];
    #pragma unroll
    for (int mi = 0; mi < 4; mi++) {
        af0[mi] = *(const v4i*)(abase + (size_t)0 * 16384 + mi * 1024);
        af1[mi] = *(const v4i*)(abase + (size_t)1 * 16384 + mi * 1024);
        af2[mi] = *(const v4i*)(abase + (size_t)2 * 16384 + mi * 1024);
        af3[mi] = *(const v4i*)(abase + (size_t)3 * 16384 + mi * 1024);
    }

    // Tap-walking state for t=0 (dh=-1, dw=-1): window corner (r_, c_) local.
    int pixb[7], key[7];
    #pragma unroll
    for (int ni = 0; ni < 7; ni++) {
        int n  = ni * 16 + l15;
        int r_ = n / 56;
        int c_ = n - r_ * 56;
        pixb[ni] = (r_ * 58 + c_) * 256;
        key[ni]  = c_ & 15;
    }

    __syncthreads();   // drains vmcnt(0): LDS-DMA chunks + af loads all ready

    v4i acc[4][7] = {};

// STEP: load bf for sub-step S, run 28 MFMAs (priority-boosted) on the
// resident AF buffer, then reload AF with K-chunk t4+S+4 (affine, pad-safe).
#define STEP(S, AF)                                                            \
    {                                                                          \
        v4i bf[7];                                                             \
        _Pragma("unroll")                                                      \
        for (int ni = 0; ni < 7; ni++)                                         \
            bf[ni] = *(const v4i*)(lds + pixb[ni] +                            \
                                   ((((S) * 4 + l4) ^ key[ni]) << 4));         \
        __builtin_amdgcn_s_setprio(1);                                         \
        _Pragma("unroll")                                                      \
        for (int ni = 0; ni < 7; ni++) {                                       \
            _Pragma("unroll")                                                  \
            for (int mi = 0; mi < 4; mi++)                                     \
                acc[mi][ni] = __builtin_amdgcn_mfma_i32_16x16x64_i8(           \
                    AF[mi], bf[ni], acc[mi][ni], 0, 0, 0);                     \
        }                                                                      \
        __builtin_amdgcn_s_setprio(0);                                         \
        {                                                                      \
            const uint8_t* ap = abase + (size_t)(t4 + (S) + 4) * 16384;        \
            _Pragma("unroll")                                                  \
            for (int mi = 0; mi < 4; mi++)                                     \
                AF[mi] = *(const v4i*)(ap + mi * 1024);                        \
        }                                                                      \
    }

    #pragma unroll 1
    for (int t = 0; t < 9; t++) {
        const int t4 = t * 4;
        STEP(0, af0)
        STEP(1, af1)
        STEP(2, af2)
        STEP(3, af3)
        // Tap-walk t -> t+1: dw cycles -1,0,1 (ddw=+1, dtoff=+256), wrapping
        // at t=2,5 (ddw=-2, dtoff=(58-2)*256); t=8 is the end (no-op).
        const int wrap  = (t == 2 || t == 5);
        const int dtoff = (t == 8) ? 0 : (wrap ? 56 * 256 : 256);
        const int ddw   = (t == 8) ? 0 : (wrap ? -2 : 1);
        #pragma unroll
        for (int ni = 0; ni < 7; ni++) {
            pixb[ni] += dtoff;
            key[ni]   = (key[ni] + ddw) & 15;
        }
    }
#undef STEP

    // mean(|clip(w)|) from the 72 per-block partials (uniform, cheap).
    float wabs = 0.0f;
    #pragma unroll
    for (int j = 0; j < 72; j++) wabs += wsf[F_WPART + j];
    const float mv = wabs * (1.0f / (float)WELEMS);

    const int co_w = wid * 64;
    const int pbase = b * (Cn * HWn) + y0 * 56;

    // Epilogue: scale + shortcut + store + per-channel partial stats.
    float ssum[4][4] = {}, ssq[4][4] = {};
    #pragma unroll
    for (int mi = 0; mi < 4; mi++) {
        #pragma unroll
        for (int ni = 0; ni < 7; ni++) {
            v4i a = acc[mi][ni];
            #pragma unroll
            for (int q = 0; q < 4; q++) {
                int co = co_w + mi * 16 + l4 * 4 + q;
                size_t idx = (size_t)pbase + (size_t)co * HWn + (ni * 16 + l15);
                float val = fmaf(mv, (float)a[q], x[idx]);
                out[idx] = val;
                ssum[mi][q] += val;
                ssq[mi][q]  += val * val;
            }
        }
    }
    // Reduce across the 16 lanes (l15) sharing each channel, then atomics.
    #pragma unroll
    for (int mi = 0; mi < 4; mi++) {
        #pragma unroll
        for (int q = 0; q < 4; q++) {
            float s = ssum[mi][q], sq = ssq[mi][q];
            #pragma unroll
            for (int off = 1; off < 16; off <<= 1) {
                s  += __shfl_xor(s, off);
                sq += __shfl_xor(sq, off);
            }
            if (l15 == 0) {
                int co = co_w + mi * 16 + l4 * 4 + q;
                atomicAdd(&wsf[F_SUM + co], s);
                atomicAdd(&wsf[F_SQ  + co], sq);
            }
        }
    }
}

// ---------------------------------------------------------------------------
// BN finalize (per-plane, from fused stats) + normalize + ReLU, in place.
__global__ void epilogue_kernel(float* __restrict__ out,
                                const float* __restrict__ wsf,
                                const float* __restrict__ g,
                                const float* __restrict__ bt) {
    int plane = blockIdx.x;   // b*256 + c
    int c = plane & 255;
    const float n = (float)(Bn * HWn);
    float mean = wsf[F_SUM + c] / n;
    float var  = wsf[F_SQ + c] / n - mean * mean;
    float sc = g[c] * rsqrtf(var + EPSv);
    float sh = bt[c] - mean * sc;
    float4* o4 = (float4*)(out + (size_t)plane * HWn);
    for (int i = threadIdx.x; i < HWn / 4; i += 256) {
        float4 v = o4[i];
        v.x = fmaxf(fmaf(v.x, sc, sh), 0.0f);
        v.y = fmaxf(fmaf(v.y, sc, sh), 0.0f);
        v.z = fmaxf(fmaf(v.z, sc, sh), 0.0f);
        v.w = fmaxf(fmaf(v.w, sc, sh), 0.0f);
        o4[i] = v;
    }
}

// ---------------------------------------------------------------------------
extern "C" void kernel_launch(void* const* d_in, const int* in_sizes, int n_in,
                              void* d_out, int out_size, void* d_ws, size_t ws_size,
                              hipStream_t stream) {
    const float* x     = (const float*)d_in[0];
    const float* w     = (const float*)d_in[1];
    const float* gamma = (const float*)d_in[2];
    const float* beta  = (const float*)d_in[3];
    float* out = (float*)d_out;

    float*   wsf = (float*)d_ws;
    uint8_t* wpk = (uint8_t*)d_ws + WPK_OFF;
    uint8_t* act = (uint8_t*)d_ws + ACT_OFF;

    pack_all<<<dim3(917), dim3(128), 0, stream>>>(x, w, wsf, wpk, act);
    conv_mfma<<<dim3(896), dim3(256), 0, stream>>>(act, wpk, x, wsf, out);
    epilogue_kernel<<<dim3(Bn * Cn), dim3(256), 0, stream>>>(out, wsf, gamma, beta);
}